// Round 10
// baseline (1929.531 us; speedup 1.0000x reference)
//
#include <hip/hip_runtime.h>
#include <math.h>

#define HD    64
#define SLEN  256
#define BATCH 1024
#define TBB   16
#define NB    (BATCH / TBB)   // 64 blocks
#define NT    256             // 4 waves, column-ownership, 1 wave/SIMD (VERIFIED operating point)
#define MEMN  10
#define LASTT (SLEN - MEMN)   // 246

typedef short bf16x8 __attribute__((ext_vector_type(8)));
typedef float f32x4  __attribute__((ext_vector_type(4)));
typedef unsigned short u16x4 __attribute__((ext_vector_type(4)));

#define MFMA16(a, b, c) __builtin_amdgcn_mfma_f32_16x16x32_bf16((a), (b), (c), 0, 0, 0)

// ws layout (ushort elements unless noted) — unchanged:
//   WgH : [0        .. 122880)   frag-packed Wg hi, 2 layers x 20 tiles x 6 ks x 64 lanes x 8
//   WgL : [122880   .. 245760)
//   WsH : [245760   .. 262144)   frag-packed Ws hi, 2 layers x 4 tiles x 4 ks x 64 x 8
//   WsL : [262144   .. 278528)
//   WsR : byte 557056, 128 floats (delta row of Ws0, Ws1)
#define OFF_WGL 122880
#define OFF_WSH 245760
#define OFF_WSL 262144
#define OFF_WSR_BYTES 557056

__device__ __forceinline__ unsigned short f2bf(float f) {
  unsigned u = __float_as_uint(f);
  u += 0x7fffu + ((u >> 16) & 1u);   // round-to-nearest-even
  return (unsigned short)(u >> 16);
}
__device__ __forceinline__ float bf2f(unsigned short h) {
  return __uint_as_float(((unsigned)h) << 16);
}

__device__ __forceinline__ float frcp(float x) {
#if __has_builtin(__builtin_amdgcn_rcpf)
  return __builtin_amdgcn_rcpf(x);
#else
  return 1.0f / x;
#endif
}
__device__ __forceinline__ float fsigm(float v) { return frcp(1.0f + __expf(-v)); }
__device__ __forceinline__ float ftanh(float v) { return 2.0f * frcp(1.0f + __expf(-2.0f * v)) - 1.0f; }

// raw barrier: waits LDS ops only; global loads (weights, x prefetch) stay in flight
__device__ __forceinline__ void bar_lds() {
  asm volatile("s_waitcnt lgkmcnt(0)" ::: "memory");
  __builtin_amdgcn_s_barrier();
  asm volatile("" ::: "memory");
}

// ---------------- prep: pack weights into MFMA B-fragment order, bf16 hi/lo ----------------
__global__ void __launch_bounds__(256)
prep_pack(const float* __restrict__ Wg0, const float* __restrict__ Wg1,
          const float* __restrict__ Ws0, const float* __restrict__ Ws1,
          unsigned short* __restrict__ ws)
{
  const int idx = blockIdx.x * 256 + threadIdx.x;
  const int NWG = 2 * 20 * 6 * 64 * 8;  // 122880
  const int NWS = 2 * 4 * 4 * 64 * 8;   // 16384
  if (idx < NWG) {
    int L = idx / 61440, r0 = idx % 61440;
    int tile = r0 / 3072, r1 = r0 % 3072;
    int ks = r1 / 512, r2 = r1 % 512;
    int lane = r2 / 8, j = r2 % 8;
    int row = ks * 32 + (lane >> 4) * 8 + j;    // k index (<192)
    int col = tile * 16 + (lane & 15);          // gate col (<320)
    float v = (L ? Wg1 : Wg0)[row * 320 + col];
    unsigned short h = f2bf(v);
    ws[idx] = h;
    ws[OFF_WGL + idx] = f2bf(v - bf2f(h));
  } else if (idx < NWG + NWS) {
    int k = idx - NWG;
    int L = k / 8192, r0 = k % 8192;
    int tile = r0 / 2048, r1 = r0 % 2048;
    int ks = r1 / 512, r2 = r1 % 512;
    int lane = r2 / 8, j = r2 % 8;
    int row = ks * 32 + (lane >> 4) * 8 + j;    // k (<128)
    int col = tile * 16 + (lane & 15);          // s col (<64)
    float v = (L ? Ws1 : Ws0)[row * 64 + col];
    unsigned short h = f2bf(v);
    ws[OFF_WSH + k] = h;
    ws[OFF_WSL + k] = f2bf(v - bf2f(h));
  } else if (idx < NWG + NWS + 128) {
    int k = idx - NWG - NWS;
    int L = k / 64, c = k % 64;
    float* wsr = (float*)((char*)ws + OFF_WSR_BYTES);
    wsr[k] = (L ? Ws1 : Ws0)[128 * 64 + c];     // delta row
  }
}

// ---------------- main fused kernel ----------------
// LAYER-PIPELINED: at tick k, layer 0 runs step k while layer 1 runs step k-1
// (legal: L0(k) depends only on h0(k-1),x(k); L1(k-1) on h0(k-1),h1(k-2)).
// The two chains are independent -> each fills the other's stalls; 2 barriers/tick.
// Xb row stride 216 ushorts = 432 B (16B-aligned rows; banks land 2-way = free)
// LDS budget: 27,648 (Xb) + 81,920 (WgC) + 40,960 (Hm) + 128 (dlt) + 8,704 = 159,360 B.
struct __align__(16) Smem {
  unsigned short XbH[2][16][216];       // [layer][row][k col]: 0:64 h, 64:128 in, 128:192 s (hi)
  unsigned short XbL[2][16][216];       // lo
  unsigned short WgC[2][5][4][2][512];  // ks0 gate-weight cache [L][gate][tile][hi/lo][frag]
  float Hm[MEMN][16][64];               // last 10 h1 (fp32)
  float dlt[2][16];                     // double-buffered delta (parity = step index & 1)
  float h1s[16][68];
  float c1s[16][68];                    // epilogue: also reused as es (race-free, see below)
};

__global__ void __launch_bounds__(NT, 1)
thlstm_mfma(const float* __restrict__ x, const unsigned short* __restrict__ wpack,
            const float* __restrict__ bs0, const float* __restrict__ bg0,
            const float* __restrict__ bs1, const float* __restrict__ bg1,
            const float* __restrict__ Waq, const float* __restrict__ gbaq,
            const float* __restrict__ Wah, const float* __restrict__ gbah,
            const float* __restrict__ gba,  const float* __restrict__ gv,
            const float* __restrict__ Wint, const float* __restrict__ gbint,
            float* __restrict__ out)
{
  __shared__ Smem sm;
  const int tid = threadIdx.x;
  const int w = tid >> 6, l = tid & 63;
  const int lg = l >> 4, lr = l & 15;
  const int c = w * 16 + lr;              // owned output column (0..63 within HD)
  const int b0 = blockIdx.x * TBB;
  const int xrow = tid >> 4, xq = tid & 15;  // x-staging mapping: 16 rows x 16 quads

  const unsigned short* WgH = wpack;
  const unsigned short* WgL = wpack + OFF_WGL;
  const unsigned short* WsH = wpack + OFF_WSH;
  const unsigned short* WsL = wpack + OFF_WSL;
  const float* WsR = (const float*)((const char*)wpack + OFF_WSR_BYTES);

  // init LDS (h=0 at t=0; padding cols stay 0; Xb[1][0:64]=h1(-1)=0)
  for (int i = tid; i < 2 * 16 * 216; i += NT) {
    ((unsigned short*)sm.XbH)[i] = 0;
    ((unsigned short*)sm.XbL)[i] = 0;
  }
  // fill ks0 gate-weight cache: 80 frags x 512 ushorts, loaded ONCE
  for (int i = tid; i < 5120; i += NT) {
    const int chunk = i & 63, frag = i >> 6;
    const int p = frag & 1, tt = (frag >> 1) & 3;
    const int g = (frag >> 3) % 5, L = (frag >> 3) / 5;
    const unsigned short* src = (p ? WgL : WgH) + ((L * 20 + g * 4 + tt) * 6 + 0) * 512 + chunk * 8;
    *(bf16x8*)&sm.WgC[L][g][tt][p][chunk * 8] = *(const bf16x8*)src;
  }
  if (xq == 0) { sm.dlt[0][xrow] = 0.f; sm.dlt[1][xrow] = 0.f; }

  // ---- resident weights (224 VGPRs): Ws (both layers) + gate ks4..5 tail (both layers)
  bf16x8 wsW[2][4][2];       // [L][ks][hi/lo]
  bf16x8 wgT[2][5][2][2];    // [L][gate][ks-4][hi/lo]
#pragma unroll
  for (int L = 0; L < 2; ++L) {
#pragma unroll
    for (int ks = 0; ks < 4; ++ks) {
      const int o = ((L * 4 + w) * 4 + ks) * 512 + l * 8;
      wsW[L][ks][0] = *(const bf16x8*)(WsH + o);
      wsW[L][ks][1] = *(const bf16x8*)(WsL + o);
    }
#pragma unroll
    for (int g = 0; g < 5; ++g)
#pragma unroll
      for (int k2 = 0; k2 < 2; ++k2) {
        const int o = ((L * 20 + g * 4 + w) * 6 + 4 + k2) * 512 + l * 8;
        wgT[L][g][k2][0] = *(const bf16x8*)(WgH + o);
        wgT[L][g][k2][1] = *(const bf16x8*)(WgL + o);
      }
  }
  // per-lane resident biases (column is fixed per lane)
  float bsr[2]  = { bs0[c], bs1[c] };
  float wsrr[2] = { WsR[c], WsR[64 + c] };
  float bgr[2][5];
#pragma unroll
  for (int g = 0; g < 5; ++g) { bgr[0][g] = bg0[g * 64 + c]; bgr[1][g] = bg1[g * 64 + c]; }

  // ---- x(0) stage + prefetch x(1)
  f32x4 xreg = *(const f32x4*)&x[((size_t)(b0 + xrow) * SLEN + 0) * HD + xq * 4];
  float prev0 = xreg[0];
  {
    u16x4 ph, pl;
#pragma unroll
    for (int k = 0; k < 4; ++k) {
      unsigned short hh = f2bf(xreg[k]);
      ph[k] = hh; pl[k] = f2bf(xreg[k] - bf2f(hh));
    }
    *(u16x4*)&sm.XbH[0][xrow][64 + xq * 4] = ph;
    *(u16x4*)&sm.XbL[0][xrow][64 + xq * 4] = pl;
  }
  bar_lds();
  xreg = *(const f32x4*)&x[((size_t)(b0 + xrow) * SLEN + 1) * HD + xq * 4];

  float cst[2][4] = {{0.f,0.f,0.f,0.f},{0.f,0.f,0.f,0.f}};
  float h1v[4] = {0.f,0.f,0.f,0.f};

  // ================= peeled tick 0: L0(0) only =================
  {
    bf16x8 w1H[5], w1L[5];
#pragma unroll
    for (int g = 0; g < 5; ++g) {
      const int o1 = ((g * 4 + w) * 6 + 1) * 512 + l * 8;
      w1H[g] = *(const bf16x8*)(WgH + o1);
      w1L[g] = *(const bf16x8*)(WgL + o1);
    }
    bf16x8 aH[4], aL[4];
#pragma unroll
    for (int ks = 0; ks < 4; ++ks) {
      aH[ks] = *(const bf16x8*)&sm.XbH[0][lr][ks * 32 + lg * 8];
      aL[ks] = *(const bf16x8*)&sm.XbL[0][lr][ks * 32 + lg * 8];
    }
    f32x4 sHH = {0,0,0,0}, sHL = {0,0,0,0}, sLH = {0,0,0,0};
#pragma unroll
    for (int ks = 0; ks < 4; ++ks) {
      sHH = MFMA16(aH[ks], wsW[0][ks][0], sHH);
      sHL = MFMA16(aH[ks], wsW[0][ks][1], sHL);
      sLH = MFMA16(aL[ks], wsW[0][ks][0], sLH);
    }
    f32x4 gacc[5];
#pragma unroll
    for (int g = 0; g < 5; ++g) {
      bf16x8 cH = *(const bf16x8*)&sm.WgC[0][g][w][0][l * 8];
      bf16x8 cL = *(const bf16x8*)&sm.WgC[0][g][w][1][l * 8];
      f32x4 acc = {0,0,0,0};
      acc = MFMA16(aH[0], cH, acc);
      acc = MFMA16(aH[0], cL, acc);
      acc = MFMA16(aL[0], cH, acc);
      gacc[g] = acc;
    }
    bf16x8 w2H[5], w2L[5];
#pragma unroll
    for (int g = 0; g < 5; ++g) {
      const int o2 = ((g * 4 + w) * 6 + 2) * 512 + l * 8;
      w2H[g] = *(const bf16x8*)(WgH + o2);
      w2L[g] = *(const bf16x8*)(WgL + o2);
      gacc[g] = MFMA16(aH[1], w1H[g], gacc[g]);
      gacc[g] = MFMA16(aH[1], w1L[g], gacc[g]);
      gacc[g] = MFMA16(aL[1], w1H[g], gacc[g]);
    }
    f32x4 sacc = (sHH + sHL) + sLH;
    float sv[4];
#pragma unroll
    for (int q = 0; q < 4; ++q) {
      const int r = lg * 4 + q;
      sv[q] = ftanh(sacc[q] + bsr[0]);   // dlt(0) == 0
      unsigned short hh = f2bf(sv[q]);
      sm.XbH[0][r][128 + c] = hh;
      sm.XbL[0][r][128 + c] = f2bf(sv[q] - bf2f(hh));
    }
#pragma unroll
    for (int g = 0; g < 5; ++g) {
      gacc[g] = MFMA16(aH[2], w2H[g], gacc[g]);
      gacc[g] = MFMA16(aH[2], w2L[g], gacc[g]);
      gacc[g] = MFMA16(aL[2], w2H[g], gacc[g]);
    }
    bar_lds();
    bf16x8 w3H[5], w3L[5];
#pragma unroll
    for (int g = 0; g < 5; ++g) {
      const int o3 = ((g * 4 + w) * 6 + 3) * 512 + l * 8;
      w3H[g] = *(const bf16x8*)(WgH + o3);
      w3L[g] = *(const bf16x8*)(WgL + o3);
    }
    bf16x8 sHf[2], sLf[2];
#pragma unroll
    for (int k2 = 0; k2 < 2; ++k2) {
      sHf[k2] = *(const bf16x8*)&sm.XbH[0][lr][128 + k2 * 32 + lg * 8];
      sLf[k2] = *(const bf16x8*)&sm.XbL[0][lr][128 + k2 * 32 + lg * 8];
    }
#pragma unroll
    for (int k2 = 0; k2 < 2; ++k2)
#pragma unroll
      for (int g = 0; g < 5; ++g) {
        gacc[g] = MFMA16(sHf[k2], wgT[0][g][k2][0], gacc[g]);
        gacc[g] = MFMA16(sHf[k2], wgT[0][g][k2][1], gacc[g]);
        gacc[g] = MFMA16(sLf[k2], wgT[0][g][k2][0], gacc[g]);
      }
#pragma unroll
    for (int g = 0; g < 5; ++g) {
      gacc[g] = MFMA16(aH[3], w3H[g], gacc[g]);
      gacc[g] = MFMA16(aH[3], w3L[g], gacc[g]);
      gacc[g] = MFMA16(aL[3], w3H[g], gacc[g]);
    }
#pragma unroll
    for (int q = 0; q < 4; ++q) {
      const int r = lg * 4 + q;
      const float fg = fsigm(gacc[0][q] + bgr[0][0]);
      const float ig = fsigm(gacc[1][q] + bgr[0][1]);
      const float Tg = fsigm(gacc[2][q] + bgr[0][2]);
      const float ug = ftanh(gacc[3][q] + bgr[0][3]);
      const float og = fsigm(gacc[4][q] + bgr[0][4]);
      const float cn = fg * cst[0][q] + ig * ug + Tg * sv[q];
      cst[0][q] = cn;
      const float hn = og * ftanh(cn);
      const unsigned short hh = f2bf(hn), hl = f2bf(hn - bf2f(hh));
      sm.XbH[0][r][c] = hh;      sm.XbL[0][r][c] = hl;
      sm.XbH[1][r][64 + c] = hh; sm.XbL[1][r][64 + c] = hl;
    }
    // stage x(1), delta(1); prefetch x(2)
    if (xq == 0) { sm.dlt[1][xrow] = xreg[0] - prev0; prev0 = xreg[0]; }
    {
      u16x4 ph, pl;
#pragma unroll
      for (int k = 0; k < 4; ++k) {
        unsigned short hh = f2bf(xreg[k]);
        ph[k] = hh; pl[k] = f2bf(xreg[k] - bf2f(hh));
      }
      *(u16x4*)&sm.XbH[0][xrow][64 + xq * 4] = ph;
      *(u16x4*)&sm.XbL[0][xrow][64 + xq * 4] = pl;
    }
    xreg = *(const f32x4*)&x[((size_t)(b0 + xrow) * SLEN + 2) * HD + xq * 4];
    bar_lds();
  }

  // ================= main pipelined loop: tick k = L0(k) + L1(k-1) =================
  for (int tick = 1; tick < SLEN; ++tick) {
    // ---------------- PHASE A ----------------
    bf16x8 w1H[2][5], w1L[2][5];
#pragma unroll
    for (int Lc = 0; Lc < 2; ++Lc)
#pragma unroll
      for (int g = 0; g < 5; ++g) {
        const int o1 = ((Lc * 20 + g * 4 + w) * 6 + 1) * 512 + l * 8;
        w1H[Lc][g] = *(const bf16x8*)(WgH + o1);
        w1L[Lc][g] = *(const bf16x8*)(WgL + o1);
      }
    bf16x8 aH[2][4], aL[2][4];
#pragma unroll
    for (int Lc = 0; Lc < 2; ++Lc)
#pragma unroll
      for (int ks = 0; ks < 4; ++ks) {
        aH[Lc][ks] = *(const bf16x8*)&sm.XbH[Lc][lr][ks * 32 + lg * 8];
        aL[Lc][ks] = *(const bf16x8*)&sm.XbL[Lc][lr][ks * 32 + lg * 8];
      }
    // s: per layer, 3 independent 4-chains — the two layers' chains interleave freely
    f32x4 sHH[2], sHL[2], sLH[2];
#pragma unroll
    for (int Lc = 0; Lc < 2; ++Lc) {
      sHH[Lc] = (f32x4){0,0,0,0}; sHL[Lc] = (f32x4){0,0,0,0}; sLH[Lc] = (f32x4){0,0,0,0};
#pragma unroll
      for (int ks = 0; ks < 4; ++ks) {
        sHH[Lc] = MFMA16(aH[Lc][ks], wsW[Lc][ks][0], sHH[Lc]);
        sHL[Lc] = MFMA16(aH[Lc][ks], wsW[Lc][ks][1], sHL[Lc]);
        sLH[Lc] = MFMA16(aL[Lc][ks], wsW[Lc][ks][0], sLH[Lc]);
      }
    }
    // gates ks0 (LDS cache), both layers
    f32x4 gacc[2][5];
#pragma unroll
    for (int Lc = 0; Lc < 2; ++Lc)
#pragma unroll
      for (int g = 0; g < 5; ++g) {
        bf16x8 cH = *(const bf16x8*)&sm.WgC[Lc][g][w][0][l * 8];
        bf16x8 cL = *(const bf16x8*)&sm.WgC[Lc][g][w][1][l * 8];
        f32x4 acc = {0,0,0,0};
        acc = MFMA16(aH[Lc][0], cH, acc);
        acc = MFMA16(aH[Lc][0], cL, acc);
        acc = MFMA16(aL[Lc][0], cH, acc);
        gacc[Lc][g] = acc;
      }
    // consume ks1; issue ks2
    bf16x8 w2H[2][5], w2L[2][5];
#pragma unroll
    for (int Lc = 0; Lc < 2; ++Lc)
#pragma unroll
      for (int g = 0; g < 5; ++g) {
        const int o2 = ((Lc * 20 + g * 4 + w) * 6 + 2) * 512 + l * 8;
        w2H[Lc][g] = *(const bf16x8*)(WgH + o2);
        w2L[Lc][g] = *(const bf16x8*)(WgL + o2);
        gacc[Lc][g] = MFMA16(aH[Lc][1], w1H[Lc][g], gacc[Lc][g]);
        gacc[Lc][g] = MFMA16(aH[Lc][1], w1L[Lc][g], gacc[Lc][g]);
        gacc[Lc][g] = MFMA16(aL[Lc][1], w1H[Lc][g], gacc[Lc][g]);
      }
    // finish s, publish (L0 uses delta(tick), L1 uses delta(tick-1))
    float sv[2][4];
    const float* dltA = sm.dlt[tick & 1];
    const float* dltB = sm.dlt[(tick & 1) ^ 1];
#pragma unroll
    for (int Lc = 0; Lc < 2; ++Lc) {
      const float* dltc = Lc ? dltB : dltA;
      f32x4 sacc = (sHH[Lc] + sHL[Lc]) + sLH[Lc];
#pragma unroll
      for (int q = 0; q < 4; ++q) {
        const int r = lg * 4 + q;
        sv[Lc][q] = ftanh(sacc[q] + bsr[Lc] + dltc[r] * wsrr[Lc]);
        unsigned short hh = f2bf(sv[Lc][q]);
        sm.XbH[Lc][r][128 + c] = hh;
        sm.XbL[Lc][r][128 + c] = f2bf(sv[Lc][q] - bf2f(hh));
      }
    }
    // consume ks2 before the barrier
#pragma unroll
    for (int Lc = 0; Lc < 2; ++Lc)
#pragma unroll
      for (int g = 0; g < 5; ++g) {
        gacc[Lc][g] = MFMA16(aH[Lc][2], w2H[Lc][g], gacc[Lc][g]);
        gacc[Lc][g] = MFMA16(aH[Lc][2], w2L[Lc][g], gacc[Lc][g]);
        gacc[Lc][g] = MFMA16(aL[Lc][2], w2H[Lc][g], gacc[Lc][g]);
      }
    bar_lds();   // --- bar1: both layers' s published; streams stay in flight

    // ---------------- PHASE B ----------------
    bf16x8 w3H[2][5], w3L[2][5];
#pragma unroll
    for (int Lc = 0; Lc < 2; ++Lc)
#pragma unroll
      for (int g = 0; g < 5; ++g) {
        const int o3 = ((Lc * 20 + g * 4 + w) * 6 + 3) * 512 + l * 8;
        w3H[Lc][g] = *(const bf16x8*)(WgH + o3);
        w3L[Lc][g] = *(const bf16x8*)(WgL + o3);
      }
    bf16x8 sHf[2][2], sLf[2][2];
#pragma unroll
    for (int Lc = 0; Lc < 2; ++Lc)
#pragma unroll
      for (int k2 = 0; k2 < 2; ++k2) {
        sHf[Lc][k2] = *(const bf16x8*)&sm.XbH[Lc][lr][128 + k2 * 32 + lg * 8];
        sLf[Lc][k2] = *(const bf16x8*)&sm.XbL[Lc][lr][128 + k2 * 32 + lg * 8];
      }
    // tails (resident weights) — cover ks3 delivery
#pragma unroll
    for (int Lc = 0; Lc < 2; ++Lc)
#pragma unroll
      for (int k2 = 0; k2 < 2; ++k2)
#pragma unroll
        for (int g = 0; g < 5; ++g) {
          gacc[Lc][g] = MFMA16(sHf[Lc][k2], wgT[Lc][g][k2][0], gacc[Lc][g]);
          gacc[Lc][g] = MFMA16(sHf[Lc][k2], wgT[Lc][g][k2][1], gacc[Lc][g]);
          gacc[Lc][g] = MFMA16(sLf[Lc][k2], wgT[Lc][g][k2][0], gacc[Lc][g]);
        }
    // consume ks3
#pragma unroll
    for (int Lc = 0; Lc < 2; ++Lc)
#pragma unroll
      for (int g = 0; g < 5; ++g) {
        gacc[Lc][g] = MFMA16(aH[Lc][3], w3H[Lc][g], gacc[Lc][g]);
        gacc[Lc][g] = MFMA16(aH[Lc][3], w3L[Lc][g], gacc[Lc][g]);
        gacc[Lc][g] = MFMA16(aL[Lc][3], w3H[Lc][g], gacc[Lc][g]);
      }
    // cell updates (both layers; chains independent)
#pragma unroll
    for (int q = 0; q < 4; ++q) {
      const int r = lg * 4 + q;
      {
        const float fg = fsigm(gacc[0][0][q] + bgr[0][0]);
        const float ig = fsigm(gacc[0][1][q] + bgr[0][1]);
        const float Tg = fsigm(gacc[0][2][q] + bgr[0][2]);
        const float ug = ftanh(gacc[0][3][q] + bgr[0][3]);
        const float og = fsigm(gacc[0][4][q] + bgr[0][4]);
        const float cn = fg * cst[0][q] + ig * ug + Tg * sv[0][q];
        cst[0][q] = cn;
        const float hn = og * ftanh(cn);
        const unsigned short hh = f2bf(hn), hl = f2bf(hn - bf2f(hh));
        sm.XbH[0][r][c] = hh;      sm.XbL[0][r][c] = hl;       // h0(tick) for L0(tick+1)
        sm.XbH[1][r][64 + c] = hh; sm.XbL[1][r][64 + c] = hl;  // input for L1(tick) next tick
      }
      {
        const float fg = fsigm(gacc[1][0][q] + bgr[1][0]);
        const float ig = fsigm(gacc[1][1][q] + bgr[1][1]);
        const float Tg = fsigm(gacc[1][2][q] + bgr[1][2]);
        const float ug = ftanh(gacc[1][3][q] + bgr[1][3]);
        const float og = fsigm(gacc[1][4][q] + bgr[1][4]);
        const float cn = fg * cst[1][q] + ig * ug + Tg * sv[1][q];
        cst[1][q] = cn;
        const float hn = og * ftanh(cn);
        const unsigned short hh = f2bf(hn), hl = f2bf(hn - bf2f(hh));
        sm.XbH[1][r][c] = hh;      sm.XbL[1][r][c] = hl;       // h1(tick-1)
        if (tick - 1 >= LASTT) sm.Hm[tick - 1 - LASTT][r][c] = hn;
      }
    }
    // stage x(tick+1) + delta(tick+1); prefetch x(tick+2)
    if (xq == 0) { sm.dlt[(tick + 1) & 1][xrow] = xreg[0] - prev0; prev0 = xreg[0]; }
    {
      u16x4 ph, pl;
#pragma unroll
      for (int k = 0; k < 4; ++k) {
        unsigned short hh = f2bf(xreg[k]);
        ph[k] = hh; pl[k] = f2bf(xreg[k] - bf2f(hh));
      }
      *(u16x4*)&sm.XbH[0][xrow][64 + xq * 4] = ph;
      *(u16x4*)&sm.XbL[0][xrow][64 + xq * 4] = pl;
    }
    {
      const int tn = (tick + 2 < SLEN) ? (tick + 2) : (SLEN - 1);
      xreg = *(const f32x4*)&x[((size_t)(b0 + xrow) * SLEN + tn) * HD + xq * 4];
    }
    bar_lds();   // --- bar2: h0(tick), h1(tick-1), x(tick+1) all published
  }

  // ================= peeled tick SLEN: L1(SLEN-1) only =================
  {
    bf16x8 w1H[5], w1L[5];
#pragma unroll
    for (int g = 0; g < 5; ++g) {
      const int o1 = ((20 + g * 4 + w) * 6 + 1) * 512 + l * 8;
      w1H[g] = *(const bf16x8*)(WgH + o1);
      w1L[g] = *(const bf16x8*)(WgL + o1);
    }
    bf16x8 aH[4], aL[4];
#pragma unroll
    for (int ks = 0; ks < 4; ++ks) {
      aH[ks] = *(const bf16x8*)&sm.XbH[1][lr][ks * 32 + lg * 8];
      aL[ks] = *(const bf16x8*)&sm.XbL[1][lr][ks * 32 + lg * 8];
    }
    f32x4 sHH = {0,0,0,0}, sHL = {0,0,0,0}, sLH = {0,0,0,0};
#pragma unroll
    for (int ks = 0; ks < 4; ++ks) {
      sHH = MFMA16(aH[ks], wsW[1][ks][0], sHH);
      sHL = MFMA16(aH[ks], wsW[1][ks][1], sHL);
      sLH = MFMA16(aL[ks], wsW[1][ks][0], sLH);
    }
    f32x4 gacc[5];
#pragma unroll
    for (int g = 0; g < 5; ++g) {
      bf16x8 cH = *(const bf16x8*)&sm.WgC[1][g][w][0][l * 8];
      bf16x8 cL = *(const bf16x8*)&sm.WgC[1][g][w][1][l * 8];
      f32x4 acc = {0,0,0,0};
      acc = MFMA16(aH[0], cH, acc);
      acc = MFMA16(aH[0], cL, acc);
      acc = MFMA16(aL[0], cH, acc);
      gacc[g] = acc;
    }
    bf16x8 w2H[5], w2L[5];
#pragma unroll
    for (int g = 0; g < 5; ++g) {
      const int o2 = ((20 + g * 4 + w) * 6 + 2) * 512 + l * 8;
      w2H[g] = *(const bf16x8*)(WgH + o2);
      w2L[g] = *(const bf16x8*)(WgL + o2);
      gacc[g] = MFMA16(aH[1], w1H[g], gacc[g]);
      gacc[g] = MFMA16(aH[1], w1L[g], gacc[g]);
      gacc[g] = MFMA16(aL[1], w1H[g], gacc[g]);
    }
    f32x4 sacc = (sHH + sHL) + sLH;
    float sv[4];
    const float* dltc = sm.dlt[(SLEN - 1) & 1];
#pragma unroll
    for (int q = 0; q < 4; ++q) {
      const int r = lg * 4 + q;
      sv[q] = ftanh(sacc[q] + bsr[1] + dltc[r] * wsrr[1]);
      unsigned short hh = f2bf(sv[q]);
      sm.XbH[1][r][128 + c] = hh;
      sm.XbL[1][r][128 + c] = f2bf(sv[q] - bf2f(hh));
    }
#pragma unroll
    for (int g = 0; g < 5; ++g) {
      gacc[g] = MFMA16(aH[2], w2H[g], gacc[g]);
      gacc[g] = MFMA16(aH[2], w2L[g], gacc[g]);
      gacc[g] = MFMA16(aL[2], w2H[g], gacc[g]);
    }
    bar_lds();
    bf16x8 w3H[5], w3L[5];
#pragma unroll
    for (int g = 0; g < 5; ++g) {
      const int o3 = ((20 + g * 4 + w) * 6 + 3) * 512 + l * 8;
      w3H[g] = *(const bf16x8*)(WgH + o3);
      w3L[g] = *(const bf16x8*)(WgL + o3);
    }
    bf16x8 sHf[2], sLf[2];
#pragma unroll
    for (int k2 = 0; k2 < 2; ++k2) {
      sHf[k2] = *(const bf16x8*)&sm.XbH[1][lr][128 + k2 * 32 + lg * 8];
      sLf[k2] = *(const bf16x8*)&sm.XbL[1][lr][128 + k2 * 32 + lg * 8];
    }
#pragma unroll
    for (int k2 = 0; k2 < 2; ++k2)
#pragma unroll
      for (int g = 0; g < 5; ++g) {
        gacc[g] = MFMA16(sHf[k2], wgT[1][g][k2][0], gacc[g]);
        gacc[g] = MFMA16(sHf[k2], wgT[1][g][k2][1], gacc[g]);
        gacc[g] = MFMA16(sLf[k2], wgT[1][g][k2][0], gacc[g]);
      }
#pragma unroll
    for (int g = 0; g < 5; ++g) {
      gacc[g] = MFMA16(aH[3], w3H[g], gacc[g]);
      gacc[g] = MFMA16(aH[3], w3L[g], gacc[g]);
      gacc[g] = MFMA16(aL[3], w3H[g], gacc[g]);
    }
#pragma unroll
    for (int q = 0; q < 4; ++q) {
      const int r = lg * 4 + q;
      const float fg = fsigm(gacc[0][q] + bgr[1][0]);
      const float ig = fsigm(gacc[1][q] + bgr[1][1]);
      const float Tg = fsigm(gacc[2][q] + bgr[1][2]);
      const float ug = ftanh(gacc[3][q] + bgr[1][3]);
      const float og = fsigm(gacc[4][q] + bgr[1][4]);
      const float cn = fg * cst[1][q] + ig * ug + Tg * sv[q];
      cst[1][q] = cn;
      const float hn = og * ftanh(cn);
      h1v[q] = hn;
      sm.Hm[MEMN - 1][r][c] = hn;   // t = SLEN-1
    }
  }

  // ---- stage final h1/c1 from registers ----
#pragma unroll
  for (int q = 0; q < 4; ++q) {
    const int r = lg * 4 + q;
    sm.h1s[r][c] = h1v[q];
    sm.c1s[r][c] = cst[1][q];
  }
  bar_lds();

  // ---- attention epilogue: wave w handles rows 4w..4w+3; lane = output col ----
  // es overlays c1s: each wave reads c1s ONLY for its own rows (qv) and later writes
  // es ONLY to those same rows, in program order -> no cross-wave race, no extra barrier.
  float evs[4];
#pragma unroll
  for (int ri = 0; ri < 4; ++ri) {
    const int r = 4 * w + ri;
    const int j = l;
    float qv = gbaq[j];
    for (int k = 0; k < 64; ++k) qv += sm.h1s[r][k] * Waq[k * 64 + j];
    for (int k = 0; k < 64; ++k) qv += sm.c1s[r][k] * Waq[(64 + k) * 64 + j];
    float sc[MEMN];
#pragma unroll
    for (int m = 0; m < MEMN; ++m) {
      float hp = gbah[j];
      for (int k = 0; k < 64; ++k) hp += sm.Hm[m][r][k] * Wah[k * 64 + j];
      float tv = tanhf(qv + hp + gba[j]) * gv[j];
#pragma unroll
      for (int off = 32; off; off >>= 1) tv += __shfl_xor(tv, off, 64);
      sc[m] = tv;
    }
    float mx = sc[0];
#pragma unroll
    for (int m = 1; m < MEMN; ++m) mx = fmaxf(mx, sc[m]);
    float den = 0.f;
#pragma unroll
    for (int m = 0; m < MEMN; ++m) { sc[m] = expf(sc[m] - mx); den += sc[m]; }
    const float inv = 1.f / den;
    float ev = 0.f;
#pragma unroll
    for (int m = 0; m < MEMN; ++m) ev += sc[m] * sm.Hm[m][r][j];
    evs[ri] = ev * inv;
  }
  float (*es)[68] = sm.c1s;   // overlay (c1s dead for this wave's rows from here on)
#pragma unroll
  for (int ri = 0; ri < 4; ++ri) es[4 * w + ri][l] = evs[ri];
  bar_lds();
#pragma unroll
  for (int ri = 0; ri < 4; ++ri) {
    const int r = 4 * w + ri;
    const int j = l;
    float acc = gbint[j];
    for (int k = 0; k < 64; ++k) acc += sm.h1s[r][k] * Wint[k * 64 + j];
    for (int k = 0; k < 64; ++k) acc += es[r][k] * Wint[(64 + k) * 64 + j];
    out[(size_t)(b0 + r) * HD + j] = tanhf(acc);
  }
}

extern "C" void kernel_launch(void* const* d_in, const int* in_sizes, int n_in,
                              void* d_out, int out_size, void* d_ws, size_t ws_size,
                              hipStream_t stream) {
  const float* x      = (const float*)d_in[0];
  const float* Ws0    = (const float*)d_in[1];
  const float* bs0    = (const float*)d_in[2];
  const float* Wg0    = (const float*)d_in[3];
  const float* bg0    = (const float*)d_in[4];
  const float* Ws1    = (const float*)d_in[5];
  const float* bs1    = (const float*)d_in[6];
  const float* Wg1    = (const float*)d_in[7];
  const float* bg1    = (const float*)d_in[8];
  const float* Waq    = (const float*)d_in[9];
  const float* baq    = (const float*)d_in[10];
  const float* Wah    = (const float*)d_in[11];
  const float* bah    = (const float*)d_in[12];
  const float* bias_a = (const float*)d_in[13];
  const float* v      = (const float*)d_in[14];
  const float* Wint   = (const float*)d_in[15];
  const float* bint   = (const float*)d_in[16];
  float* out = (float*)d_out;

  const int total = 2 * 20 * 6 * 64 * 8 + 2 * 4 * 4 * 64 * 8 + 128;
  prep_pack<<<(total + 255) / 256, 256, 0, stream>>>(Wg0, Wg1, Ws0, Ws1,
                                                     (unsigned short*)d_ws);
  thlstm_mfma<<<NB, NT, 0, stream>>>(x, (const unsigned short*)d_ws,
                                     bs0, bg0, bs1, bg1,
                                     Waq, baq, Wah, bah, bias_a, v, Wint, bint, out);
}

// Round 11
// 1278.349 us; speedup vs baseline: 1.5094x; 1.5094x over previous
//
#include <hip/hip_runtime.h>
#include <math.h>

#define HD    64
#define SLEN  256
#define BATCH 1024
#define TBB   16
#define NB    (BATCH / TBB)   // 64 blocks
#define NT    256             // 4 waves, column-ownership, 1 wave/SIMD (VERIFIED operating point)
#define MEMN  10

typedef short bf16x8 __attribute__((ext_vector_type(8)));
typedef float f32x4  __attribute__((ext_vector_type(4)));
typedef unsigned short u16x4 __attribute__((ext_vector_type(4)));

#define MFMA16(a, b, c) __builtin_amdgcn_mfma_f32_16x16x32_bf16((a), (b), (c), 0, 0, 0)

// ws layout (ushort elements unless noted) — unchanged:
//   WgH : [0        .. 122880)   frag-packed Wg hi, 2 layers x 20 tiles x 6 ks x 64 lanes x 8
//   WgL : [122880   .. 245760)
//   WsH : [245760   .. 262144)   frag-packed Ws hi, 2 layers x 4 tiles x 4 ks x 64 x 8
//   WsL : [262144   .. 278528)
//   WsR : byte 557056, 128 floats (delta row of Ws0, Ws1)
#define OFF_WGL 122880
#define OFF_WSH 245760
#define OFF_WSL 262144
#define OFF_WSR_BYTES 557056

__device__ __forceinline__ unsigned short f2bf(float f) {
  unsigned u = __float_as_uint(f);
  u += 0x7fffu + ((u >> 16) & 1u);   // round-to-nearest-even
  return (unsigned short)(u >> 16);
}
__device__ __forceinline__ float bf2f(unsigned short h) {
  return __uint_as_float(((unsigned)h) << 16);
}

__device__ __forceinline__ float frcp(float x) {
#if __has_builtin(__builtin_amdgcn_rcpf)
  return __builtin_amdgcn_rcpf(x);
#else
  return 1.0f / x;
#endif
}
__device__ __forceinline__ float fsigm(float v) { return frcp(1.0f + __expf(-v)); }
__device__ __forceinline__ float ftanh(float v) { return 2.0f * frcp(1.0f + __expf(-2.0f * v)) - 1.0f; }

// raw barrier: waits LDS ops only; global loads (weights, x prefetch) stay in flight
__device__ __forceinline__ void bar_lds() {
  asm volatile("s_waitcnt lgkmcnt(0)" ::: "memory");
  __builtin_amdgcn_s_barrier();
  asm volatile("" ::: "memory");
}

// ---------------- prep: pack weights into MFMA B-fragment order, bf16 hi/lo ----------------
__global__ void __launch_bounds__(256)
prep_pack(const float* __restrict__ Wg0, const float* __restrict__ Wg1,
          const float* __restrict__ Ws0, const float* __restrict__ Ws1,
          unsigned short* __restrict__ ws)
{
  const int idx = blockIdx.x * 256 + threadIdx.x;
  const int NWG = 2 * 20 * 6 * 64 * 8;  // 122880
  const int NWS = 2 * 4 * 4 * 64 * 8;   // 16384
  if (idx < NWG) {
    int L = idx / 61440, r0 = idx % 61440;
    int tile = r0 / 3072, r1 = r0 % 3072;
    int ks = r1 / 512, r2 = r1 % 512;
    int lane = r2 / 8, j = r2 % 8;
    int row = ks * 32 + (lane >> 4) * 8 + j;    // k index (<192)
    int col = tile * 16 + (lane & 15);          // gate col (<320)
    float v = (L ? Wg1 : Wg0)[row * 320 + col];
    unsigned short h = f2bf(v);
    ws[idx] = h;
    ws[OFF_WGL + idx] = f2bf(v - bf2f(h));
  } else if (idx < NWG + NWS) {
    int k = idx - NWG;
    int L = k / 8192, r0 = k % 8192;
    int tile = r0 / 2048, r1 = r0 % 2048;
    int ks = r1 / 512, r2 = r1 % 512;
    int lane = r2 / 8, j = r2 % 8;
    int row = ks * 32 + (lane >> 4) * 8 + j;    // k (<128)
    int col = tile * 16 + (lane & 15);          // s col (<64)
    float v = (L ? Ws1 : Ws0)[row * 64 + col];
    unsigned short h = f2bf(v);
    ws[OFF_WSH + k] = h;
    ws[OFF_WSL + k] = f2bf(v - bf2f(h));
  } else if (idx < NWG + NWS + 128) {
    int k = idx - NWG - NWS;
    int L = k / 64, c = k % 64;
    float* wsr = (float*)((char*)ws + OFF_WSR_BYTES);
    wsr[k] = (L ? Ws1 : Ws0)[128 * 64 + c];     // delta row
  }
}

// ---------------- main fused kernel ----------------
// Xb row stride 216 ushorts = 432 B (16B-aligned rows; banks land 2-way = free)
// LDS budget: 27,648 (Xb) + 81,920 (WgC ks0 cache) + 40,960 (Hm) + 128 (dlt)
//           + 8,704 (h1s,c1s; es overlays c1s) = 159,360 B <= 163,840.
struct __align__(16) Smem {
  unsigned short XbH[2][16][216];       // [layer][row][k col]: 0:64 h, 64:128 in, 128:192 s (hi)
  unsigned short XbL[2][16][216];       // lo
  unsigned short WgC[2][5][4][2][512];  // ks0 gate-weight cache [L][gate][tile][hi/lo][frag]
  float Hm[MEMN][16][64];               // last 10 h1 (fp32)
  float dlt[2][16];                     // double-buffered delta
  float h1s[16][68];
  float c1s[16][68];                    // epilogue: also reused as es (race-free, see below)
};

__global__ void __launch_bounds__(NT, 1)
thlstm_mfma(const float* __restrict__ x, const unsigned short* __restrict__ wpack,
            const float* __restrict__ bs0, const float* __restrict__ bg0,
            const float* __restrict__ bs1, const float* __restrict__ bg1,
            const float* __restrict__ Waq, const float* __restrict__ gbaq,
            const float* __restrict__ Wah, const float* __restrict__ gbah,
            const float* __restrict__ gba,  const float* __restrict__ gv,
            const float* __restrict__ Wint, const float* __restrict__ gbint,
            float* __restrict__ out)
{
  __shared__ Smem sm;
  const int tid = threadIdx.x;
  const int w = tid >> 6, l = tid & 63;
  const int lg = l >> 4, lr = l & 15;
  const int c = w * 16 + lr;              // owned output column (0..63 within HD)
  const int b0 = blockIdx.x * TBB;
  const int xrow = tid >> 4, xq = tid & 15;  // x-staging mapping: 16 rows x 16 quads

  const unsigned short* WgH = wpack;
  const unsigned short* WgL = wpack + OFF_WGL;
  const unsigned short* WsH = wpack + OFF_WSH;
  const unsigned short* WsL = wpack + OFF_WSL;
  const float* WsR = (const float*)((const char*)wpack + OFF_WSR_BYTES);

  // init LDS (h=0 at t=0; padding cols stay 0)
  for (int i = tid; i < 2 * 16 * 216; i += NT) {
    ((unsigned short*)sm.XbH)[i] = 0;
    ((unsigned short*)sm.XbL)[i] = 0;
  }
  // fill ks0 gate-weight cache: 80 frags x 512 ushorts, loaded ONCE (saves 80KB/step from L2)
  for (int i = tid; i < 5120; i += NT) {
    const int chunk = i & 63, frag = i >> 6;
    const int p = frag & 1, tt = (frag >> 1) & 3;
    const int g = (frag >> 3) % 5, L = (frag >> 3) / 5;
    const unsigned short* src = (p ? WgL : WgH) + ((L * 20 + g * 4 + tt) * 6 + 0) * 512 + chunk * 8;
    *(bf16x8*)&sm.WgC[L][g][tt][p][chunk * 8] = *(const bf16x8*)src;
  }
  if (xq == 0) { sm.dlt[0][xrow] = 0.f; sm.dlt[1][xrow] = 0.f; }

  // ---- resident weights (224 VGPRs): Ws (both layers) + gate ks4..5 tail (both layers)
  bf16x8 wsW[2][4][2];       // [L][ks][hi/lo]
  bf16x8 wgT[2][5][2][2];    // [L][gate][ks-4][hi/lo]
#pragma unroll
  for (int L = 0; L < 2; ++L) {
#pragma unroll
    for (int ks = 0; ks < 4; ++ks) {
      const int o = ((L * 4 + w) * 4 + ks) * 512 + l * 8;
      wsW[L][ks][0] = *(const bf16x8*)(WsH + o);
      wsW[L][ks][1] = *(const bf16x8*)(WsL + o);
    }
#pragma unroll
    for (int g = 0; g < 5; ++g)
#pragma unroll
      for (int k2 = 0; k2 < 2; ++k2) {
        const int o = ((L * 20 + g * 4 + w) * 6 + 4 + k2) * 512 + l * 8;
        wgT[L][g][k2][0] = *(const bf16x8*)(WgH + o);
        wgT[L][g][k2][1] = *(const bf16x8*)(WgL + o);
      }
  }
  // per-lane resident biases (column is fixed per lane)
  float bsr[2]  = { bs0[c], bs1[c] };
  float wsrr[2] = { WsR[c], WsR[64 + c] };
  float bgr[2][5];
#pragma unroll
  for (int g = 0; g < 5; ++g) { bgr[0][g] = bg0[g * 64 + c]; bgr[1][g] = bg1[g * 64 + c]; }

  // ---- x(0) stage + prefetch x(1)
  f32x4 xreg = *(const f32x4*)&x[((size_t)(b0 + xrow) * SLEN + 0) * HD + xq * 4];
  float prev0 = xreg[0];
  {
    u16x4 ph, pl;
#pragma unroll
    for (int k = 0; k < 4; ++k) {
      unsigned short hh = f2bf(xreg[k]);
      ph[k] = hh; pl[k] = f2bf(xreg[k] - bf2f(hh));
    }
    *(u16x4*)&sm.XbH[0][xrow][64 + xq * 4] = ph;
    *(u16x4*)&sm.XbL[0][xrow][64 + xq * 4] = pl;
  }
  bar_lds();
  xreg = *(const f32x4*)&x[((size_t)(b0 + xrow) * SLEN + 1) * HD + xq * 4];

  float cst[2][4] = {{0.f,0.f,0.f,0.f},{0.f,0.f,0.f,0.f}};
  float h1v[4] = {0.f,0.f,0.f,0.f};

  // ---- loop-carried ks1 prefetch: load w1 for (t=0, L=0) ----
  bf16x8 w1H[5], w1L[5];
#pragma unroll
  for (int g = 0; g < 5; ++g) {
    const int o1 = ((0 * 20 + g * 4 + w) * 6 + 1) * 512 + l * 8;
    w1H[g] = *(const bf16x8*)(WgH + o1);
    w1L[g] = *(const bf16x8*)(WgL + o1);
  }

  for (int t = 0; t < SLEN; ++t) {
#pragma unroll
    for (int L = 0; L < 2; ++L) {
      // ---- issue streamed batches ks2, ks3 (20 loads in flight; consumed this layer) ----
      bf16x8 w2H[5], w2L[5], w3H[5], w3L[5];
#pragma unroll
      for (int g = 0; g < 5; ++g) {
        const int o2 = ((L * 20 + g * 4 + w) * 6 + 2) * 512 + l * 8;
        const int o3 = ((L * 20 + g * 4 + w) * 6 + 3) * 512 + l * 8;
        w2H[g] = *(const bf16x8*)(WgH + o2);
        w2L[g] = *(const bf16x8*)(WgL + o2);
        w3H[g] = *(const bf16x8*)(WgH + o3);
        w3L[g] = *(const bf16x8*)(WgL + o3);
      }
      // ---- a-frags ----
      bf16x8 aH[4], aL[4];
#pragma unroll
      for (int ks = 0; ks < 4; ++ks) {
        aH[ks] = *(const bf16x8*)&sm.XbH[L][lr][ks * 32 + lg * 8];
        aL[ks] = *(const bf16x8*)&sm.XbL[L][lr][ks * 32 + lg * 8];
      }
      // ---- s: 3 independent 4-chains (summed once; fp32 order change only) ----
      f32x4 sHH = {0.f,0.f,0.f,0.f}, sHL = {0.f,0.f,0.f,0.f}, sLH = {0.f,0.f,0.f,0.f};
#pragma unroll
      for (int ks = 0; ks < 4; ++ks) {
        sHH = MFMA16(aH[ks], wsW[L][ks][0], sHH);
        sHL = MFMA16(aH[ks], wsW[L][ks][1], sHL);
        sLH = MFMA16(aL[ks], wsW[L][ks][0], sLH);
      }
      // ---- gates ks0 from LDS cache (independent of s; overlaps s-chain latency) ----
      f32x4 gacc[5];
#pragma unroll
      for (int g = 0; g < 5; ++g) {
        bf16x8 cH = *(const bf16x8*)&sm.WgC[L][g][w][0][l * 8];
        bf16x8 cL = *(const bf16x8*)&sm.WgC[L][g][w][1][l * 8];
        f32x4 acc = {0.f,0.f,0.f,0.f};
        acc = MFMA16(aH[0], cH, acc);
        acc = MFMA16(aH[0], cL, acc);
        acc = MFMA16(aL[0], cH, acc);
        gacc[g] = acc;
      }
      // ---- consume ks1 (prefetched a full layer ago -> vmcnt long satisfied) ----
#pragma unroll
      for (int g = 0; g < 5; ++g) {
        gacc[g] = MFMA16(aH[1], w1H[g], gacc[g]);
        gacc[g] = MFMA16(aH[1], w1L[g], gacc[g]);
        gacc[g] = MFMA16(aL[1], w1H[g], gacc[g]);
      }
      // ---- finish s, publish (short path gates bar1) ----
      f32x4 sacc = (sHH + sHL) + sLH;
      float sv[4];
      const float* dltc = sm.dlt[t & 1];
#pragma unroll
      for (int q = 0; q < 4; ++q) {
        const int r = lg * 4 + q;
        sv[q] = ftanh(sacc[q] + bsr[L] + dltc[r] * wsrr[L]);
        unsigned short hh = f2bf(sv[q]);
        sm.XbH[L][r][128 + c] = hh;
        sm.XbL[L][r][128 + c] = f2bf(sv[q] - bf2f(hh));
      }
      // ---- consume ks2 before the barrier (covers barrier skew; frees w2 regs) ----
#pragma unroll
      for (int g = 0; g < 5; ++g) {
        gacc[g] = MFMA16(aH[2], w2H[g], gacc[g]);
        gacc[g] = MFMA16(aH[2], w2L[g], gacc[g]);
        gacc[g] = MFMA16(aL[2], w2H[g], gacc[g]);
      }
      bar_lds();   // --- bar1: s published; streams stay in flight

      // ---- consume ks3 first (issued at body start, delivered by now);
      //      s-frag ds_read latency hides under it ----
      bf16x8 sHf[2], sLf[2];
#pragma unroll
      for (int k2 = 0; k2 < 2; ++k2) {
        sHf[k2] = *(const bf16x8*)&sm.XbH[L][lr][128 + k2 * 32 + lg * 8];
        sLf[k2] = *(const bf16x8*)&sm.XbL[L][lr][128 + k2 * 32 + lg * 8];
      }
#pragma unroll
      for (int g = 0; g < 5; ++g) {
        gacc[g] = MFMA16(aH[3], w3H[g], gacc[g]);
        gacc[g] = MFMA16(aH[3], w3L[g], gacc[g]);
        gacc[g] = MFMA16(aL[3], w3H[g], gacc[g]);
      }
      // ---- tail over s (resident weights) ----
#pragma unroll
      for (int k2 = 0; k2 < 2; ++k2)
#pragma unroll
        for (int g = 0; g < 5; ++g) {
          gacc[g] = MFMA16(sHf[k2], wgT[L][g][k2][0], gacc[g]);
          gacc[g] = MFMA16(sHf[k2], wgT[L][g][k2][1], gacc[g]);
          gacc[g] = MFMA16(sLf[k2], wgT[L][g][k2][0], gacc[g]);
        }
      // ---- prefetch ks1 for the NEXT (L,t): crosses bar2, consumed next layer ----
      {
        const int nL = 1 - L;
#pragma unroll
        for (int g = 0; g < 5; ++g) {
          const int o1 = ((nL * 20 + g * 4 + w) * 6 + 1) * 512 + l * 8;
          w1H[g] = *(const bf16x8*)(WgH + o1);
          w1L[g] = *(const bf16x8*)(WgL + o1);
        }
      }
      // ---- cell update: all in registers ----
#pragma unroll
      for (int q = 0; q < 4; ++q) {
        const int r = lg * 4 + q;
        const float fg = fsigm(gacc[0][q] + bgr[L][0]);
        const float ig = fsigm(gacc[1][q] + bgr[L][1]);
        const float Tg = fsigm(gacc[2][q] + bgr[L][2]);
        const float ug = ftanh(gacc[3][q] + bgr[L][3]);
        const float og = fsigm(gacc[4][q] + bgr[L][4]);
        const float cn = fg * cst[L][q] + ig * ug + Tg * sv[q];
        cst[L][q] = cn;
        const float hn = og * ftanh(cn);
        const unsigned short hh = f2bf(hn), hl = f2bf(hn - bf2f(hh));
        if (L == 0) {
          sm.XbH[0][r][c] = hh;      sm.XbL[0][r][c] = hl;       // h0 for next step
          sm.XbH[1][r][64 + c] = hh; sm.XbL[1][r][64 + c] = hl;  // layer-1 input now
        } else {
          sm.XbH[1][r][c] = hh;      sm.XbL[1][r][c] = hl;       // h1 for next step
          h1v[q] = hn;
          if (t >= SLEN - MEMN) sm.Hm[t - (SLEN - MEMN)][r][c] = hn;
        }
      }
      if (L == 0) {
        // stage x(t+1)+dlt(t+1) (prefetched last step); issue prefetch of x(t+2)
        if (xq == 0) { sm.dlt[(t + 1) & 1][xrow] = xreg[0] - prev0; prev0 = xreg[0]; }
        u16x4 ph, pl;
#pragma unroll
        for (int k = 0; k < 4; ++k) {
          unsigned short hh = f2bf(xreg[k]);
          ph[k] = hh; pl[k] = f2bf(xreg[k] - bf2f(hh));
        }
        *(u16x4*)&sm.XbH[0][xrow][64 + xq * 4] = ph;
        *(u16x4*)&sm.XbL[0][xrow][64 + xq * 4] = pl;
        const int tn = (t + 2 < SLEN) ? (t + 2) : (SLEN - 1);
        xreg = *(const f32x4*)&x[((size_t)(b0 + xrow) * SLEN + tn) * HD + xq * 4];
      }
      bar_lds();   // --- bar2: h ready for next layer
    } // L
  } // t

  // ---- stage final h1/c1 from registers ----
#pragma unroll
  for (int q = 0; q < 4; ++q) {
    const int r = lg * 4 + q;
    sm.h1s[r][c] = h1v[q];
    sm.c1s[r][c] = cst[1][q];
  }
  bar_lds();

  // ---- attention epilogue: wave w handles rows 4w..4w+3; lane = output col ----
  // es overlays c1s: each wave reads c1s ONLY for its own rows (qv) and later writes
  // es ONLY to those same rows, in program order -> no cross-wave race, no extra barrier.
  float evs[4];
#pragma unroll
  for (int ri = 0; ri < 4; ++ri) {
    const int r = 4 * w + ri;
    const int j = l;
    float qv = gbaq[j];
    for (int k = 0; k < 64; ++k) qv += sm.h1s[r][k] * Waq[k * 64 + j];
    for (int k = 0; k < 64; ++k) qv += sm.c1s[r][k] * Waq[(64 + k) * 64 + j];
    float sc[MEMN];
#pragma unroll
    for (int m = 0; m < MEMN; ++m) {
      float hp = gbah[j];
      for (int k = 0; k < 64; ++k) hp += sm.Hm[m][r][k] * Wah[k * 64 + j];
      float tv = tanhf(qv + hp + gba[j]) * gv[j];
#pragma unroll
      for (int off = 32; off; off >>= 1) tv += __shfl_xor(tv, off, 64);
      sc[m] = tv;
    }
    float mx = sc[0];
#pragma unroll
    for (int m = 1; m < MEMN; ++m) mx = fmaxf(mx, sc[m]);
    float den = 0.f;
#pragma unroll
    for (int m = 0; m < MEMN; ++m) { sc[m] = expf(sc[m] - mx); den += sc[m]; }
    const float inv = 1.f / den;
    float ev = 0.f;
#pragma unroll
    for (int m = 0; m < MEMN; ++m) ev += sc[m] * sm.Hm[m][r][j];
    evs[ri] = ev * inv;
  }
  float (*es)[68] = sm.c1s;   // overlay (c1s dead for this wave's rows from here on)
#pragma unroll
  for (int ri = 0; ri < 4; ++ri) es[4 * w + ri][l] = evs[ri];
  bar_lds();
#pragma unroll
  for (int ri = 0; ri < 4; ++ri) {
    const int r = 4 * w + ri;
    const int j = l;
    float acc = gbint[j];
    for (int k = 0; k < 64; ++k) acc += sm.h1s[r][k] * Wint[k * 64 + j];
    for (int k = 0; k < 64; ++k) acc += es[r][k] * Wint[(64 + k) * 64 + j];
    out[(size_t)(b0 + r) * HD + j] = tanhf(acc);
  }
}

extern "C" void kernel_launch(void* const* d_in, const int* in_sizes, int n_in,
                              void* d_out, int out_size, void* d_ws, size_t ws_size,
                              hipStream_t stream) {
  const float* x      = (const float*)d_in[0];
  const float* Ws0    = (const float*)d_in[1];
  const float* bs0    = (const float*)d_in[2];
  const float* Wg0    = (const float*)d_in[3];
  const float* bg0    = (const float*)d_in[4];
  const float* Ws1    = (const float*)d_in[5];
  const float* bs1    = (const float*)d_in[6];
  const float* Wg1    = (const float*)d_in[7];
  const float* bg1    = (const float*)d_in[8];
  const float* Waq    = (const float*)d_in[9];
  const float* baq    = (const float*)d_in[10];
  const float* Wah    = (const float*)d_in[11];
  const float* bah    = (const float*)d_in[12];
  const float* bias_a = (const float*)d_in[13];
  const float* v      = (const float*)d_in[14];
  const float* Wint   = (const float*)d_in[15];
  const float* bint   = (const float*)d_in[16];
  float* out = (float*)d_out;

  const int total = 2 * 20 * 6 * 64 * 8 + 2 * 4 * 4 * 64 * 8 + 128;
  prep_pack<<<(total + 255) / 256, 256, 0, stream>>>(Wg0, Wg1, Ws0, Ws1,
                                                     (unsigned short*)d_ws);
  thlstm_mfma<<<NB, NT, 0, stream>>>(x, (const unsigned short*)d_ws,
                                     bs0, bg0, bs1, bg1,
                                     Waq, baq, Wah, bah, bias_a, v, Wint, bint, out);
}